// Round 17
// baseline (130.190 us; speedup 1.0000x reference)
//
#include <hip/hip_runtime.h>

// SelfAttentionBlock: graph transformer attention
// N=100000 nodes, E=1600000 edges, DIM=64, H=4 heads, d=16
constexpr int N_NODES = 100000;
constexpr int N_EDGES = 1600000;
constexpr int DIM = 64;
constexpr float QK_SCALE = 0.25f;   // 16^-0.5
constexpr float LOG2E = 1.4426950408889634f;
constexpr float EPS = 1e-16f;

// bucket sort: bucket = s>>8 (256 nodes each)
constexpr int NBK = (N_NODES + 255) / 256;    // 391
constexpr int BCAP = 8192;                    // u32/bucket
constexpr int SC_CHUNK = 4096;                // edges per scatter block
constexpr int SC_BLOCKS = (N_EDGES + SC_CHUNK - 1) / SC_CHUNK;  // 391 (tail n=2560, %4==0)
constexpr int QK_BLOCKS = (N_NODES + 127) / 128;                // 782 (128 nodes/block)
constexpr int TPAD = 200;                     // LDS tile row stride (shorts)

typedef __attribute__((ext_vector_type(8))) short short8;   // 8 bf16 (4 VGPR)
typedef __attribute__((ext_vector_type(4))) float f32x4;
typedef _Float16 h2 __attribute__((ext_vector_type(2)));

__device__ __forceinline__ unsigned short f32_to_bf16_rne(float f) {
    unsigned int u = __float_as_uint(f);
    u += 0x7fffu + ((u >> 16) & 1u);          // round-to-nearest-even
    return (unsigned short)(u >> 16);
}
__device__ __forceinline__ h2 as_h2(unsigned int u) { return __builtin_bit_cast(h2, u); }

#if defined(__has_builtin)
#if __has_builtin(__builtin_amdgcn_fdot2)
#define HAVE_FDOT2 1
#endif
#endif
__device__ __forceinline__ float fdot2_acc(h2 a, h2 b, float c) {
#ifdef HAVE_FDOT2
    return __builtin_amdgcn_fdot2(a, b, c, false);      // v_dot2_f32_f16
#else
    return fmaf((float)a.x, (float)b.x, fmaf((float)a.y, (float)b.y, c));
#endif
}

// sum over 4-lane quad via DPP (quad_perm xor1 = 0xB1, xor2 = 0x4E) - pure VALU
__device__ __forceinline__ float qsum4(float p) {
    int a = __builtin_amdgcn_update_dpp(0, __float_as_int(p), 0xB1, 0xF, 0xF, true);
    p += __int_as_float(a);
    int c = __builtin_amdgcn_update_dpp(0, __float_as_int(p), 0x4E, 0xF, 0xF, true);
    p += __int_as_float(c);
    return p;
}

// permuted output column jp -> original W column.
// jp 0..63: q cols. jp 64..191: interleaved kv layout [k0..3 v0..3 k4..7 ...]
__device__ __forceinline__ int orig_col(int jp) {
    if (jp < 64) return jp;
    const int p = jp - 64;
    const int chunk = p >> 3, w = p & 7;
    return (w < 4) ? (64 + chunk * 4 + w) : (128 + chunk * 4 + (w - 4));
}

// ---------------- Dispatch A: bucket_scatter (blocks 0..SC_BLOCKS-1)
//                  + prep_w (blocks SC_BLOCKS..SC_BLOCKS+63) -----------------
// prep is independent of scatter; it rides along in the same dispatch.
// Payload packed: bits 0..16 = t, bits 17..24 = s&255.
__global__ __launch_bounds__(512) void scatter_prep(const int* __restrict__ ei,
                                                    int* __restrict__ bcnt,
                                                    unsigned int* __restrict__ bbuf,
                                                    const float* __restrict__ W,
                                                    const float* __restrict__ b,
                                                    unsigned short* __restrict__ Wbt,
                                                    float* __restrict__ bb) {
    __shared__ unsigned int stage[SC_CHUNK];   // 16384 B
    __shared__ int h[NBK];
    __shared__ int lofs[NBK];
    __shared__ int gbase[NBK];
    __shared__ int wsum[8];

    if (blockIdx.x >= SC_BLOCKS) {
        // ---------- prep_w: Wbt[jp][k] bf16 (permuted cols; q cols scaled by
        // QK_SCALE*log2e for exp2-domain softmax), bias bb[jp] f32 ----------
        const int k = blockIdx.x - SC_BLOCKS;      // 0..63
        const int jp = threadIdx.x;
        if (jp < 192) {
            const int oc = orig_col(jp);
            const float sc = (jp < 64) ? QK_SCALE * LOG2E : 1.f;
            Wbt[jp * DIM + k] = f32_to_bf16_rne(W[k * 192 + oc] * sc);
            if (k == 0) bb[jp] = b[oc] * sc;
        }
        return;                                    // no barrier in this branch
    }

    // ---------- bucket scatter with LDS dense staging ----------
    const int tid = threadIdx.x;
    const int lane = tid & 63;
    const int wid = tid >> 6;
    const int e0 = blockIdx.x * SC_CHUNK;
    const int n = min(SC_CHUNK, N_EDGES - e0);     // always %4 == 0
    const int n4 = n >> 2;

    for (int i = tid; i < NBK; i += 512) h[i] = 0;
    __syncthreads();

    // phase 1: histogram of s (int4 loads)
    const int4* s4p = (const int4*)(ei + e0);
    for (int i = tid; i < n4; i += 512) {
        const int4 s4 = s4p[i];
        atomicAdd(&h[s4.x >> 8], 1);
        atomicAdd(&h[s4.y >> 8], 1);
        atomicAdd(&h[s4.z >> 8], 1);
        atomicAdd(&h[s4.w >> 8], 1);
    }
    __syncthreads();

    const int v = (tid < NBK) ? h[tid] : 0;
    int inc = v;
    #pragma unroll
    for (int d = 1; d < 64; d <<= 1) {
        int u = __shfl_up(inc, d);
        if (lane >= d) inc += u;
    }
    if (lane == 63) wsum[wid] = inc;
    __syncthreads();
    int woff = 0;
    for (int w = 0; w < wid; ++w) woff += wsum[w];
    if (tid < NBK) lofs[tid] = woff + inc - v;
    if (tid < NBK) gbase[tid] = (v > 0) ? atomicAdd(&bcnt[tid], v) : 0;
    __syncthreads();

    for (int i = tid; i < NBK; i += 512) h[i] = 0;
    __syncthreads();

    // phase 3: dense placement (int4 loads of s and t)
    const int4* t4p = (const int4*)(ei + N_EDGES + e0);
    for (int i = tid; i < n4; i += 512) {
        const int4 s4 = s4p[i];
        const int4 t4 = t4p[i];
        #pragma unroll
        for (int k = 0; k < 4; ++k) {
            const int s = (k == 0) ? s4.x : (k == 1) ? s4.y : (k == 2) ? s4.z : s4.w;
            const int t = (k == 0) ? t4.x : (k == 1) ? t4.y : (k == 2) ? t4.z : t4.w;
            const int bk = s >> 8;
            const int c = atomicAdd(&h[bk], 1);
            stage[lofs[bk] + c] = (unsigned int)t | ((unsigned int)(s & 255) << 17);
        }
    }
    __syncthreads();

    // phase 4: flush contiguous runs, buckets distributed across waves
    for (int bk = wid; bk < NBK; bk += 8) {
        const int cnt = h[bk];
        const int lo = lofs[bk];
        unsigned int* dst = bbuf + (size_t)bk * BCAP + gbase[bk];
        for (int i = lane; i < cnt; i += 64) dst[i] = stage[lo + i];
    }
}

// ---------------- Dispatch B: csr_build (blocks 0..NBK-1)
//                  + qkv projection via MFMA (remaining blocks) -------------
// The two halves are mutually independent: csr needs only scatter output,
// qkv needs only x/Wbt — overlapping them removes a serialized dispatch.
__global__ __launch_bounds__(512) void csr_qkv(const int* __restrict__ bcnt,
                                               const unsigned int* __restrict__ bbuf,
                                               int* __restrict__ deg,
                                               int* __restrict__ off,
                                               int* __restrict__ sorted_t,
                                               const float* __restrict__ x,
                                               const unsigned short* __restrict__ Wbt,
                                               const float* __restrict__ bb,
                                               unsigned short* __restrict__ qkv_t) {
    __shared__ __align__(16) char smem[128 * TPAD * 2];   // 51200 B, aliased by both branches

    if (blockIdx.x < NBK) {
        // ---------- CSR build: deg + off + sorted_t (1 block/bucket, 512 thr) --
        int* h    = (int*)smem;                     // [256]
        int* lofs = h + 256;                        // [256]
        int* wsum = lofs + 256;                     // [8]
        int* sBasep = wsum + 8;

        const int tid = threadIdx.x;
        const int lane = tid & 63;
        const int wid = tid >> 6;
        const int bk = blockIdx.x;
        const int n = bcnt[bk];

        int pre = 0;
        for (int i = tid; i < bk; i += 512) pre += bcnt[i];
        #pragma unroll
        for (int d = 1; d < 64; d <<= 1) pre += __shfl_xor(pre, d);
        if (lane == 0) wsum[wid] = pre;
        if (tid < 256) h[tid] = 0;
        __syncthreads();
        if (tid == 0) {
            int s = 0;
            #pragma unroll
            for (int w = 0; w < 8; ++w) s += wsum[w];
            *sBasep = s;
        }
        __syncthreads();
        const int sBase = *sBasep;

        const unsigned int* p = bbuf + (size_t)bk * BCAP;
        for (int i = tid; i < n; i += 512)
            atomicAdd(&h[p[i] >> 17], 1);
        __syncthreads();

        int v = 0, inc = 0;
        if (tid < 256) {
            v = h[tid];
            inc = v;
            #pragma unroll
            for (int d = 1; d < 64; d <<= 1) {
                int u = __shfl_up(inc, d);
                if (lane >= d) inc += u;
            }
            if (lane == 63) wsum[wid] = inc;
        }
        __syncthreads();
        if (tid < 256) {
            int woff = 0;
            for (int w = 0; w < wid; ++w) woff += wsum[w];
            const int exc = woff + inc - v;
            lofs[tid] = exc;
            const int node = bk * 256 + tid;
            if (node < N_NODES) { deg[node] = v; off[node] = sBase + exc; }
        }
        __syncthreads();

        if (tid < 256) h[tid] = 0;
        __syncthreads();
        int* dstbase = sorted_t + sBase;
        for (int i = tid; i < n; i += 512) {
            const unsigned int e = p[i];
            const int s8 = e >> 17;
            const int c = atomicAdd(&h[s8], 1);
            dstbase[lofs[s8] + c] = (int)(e & 0x1FFFFu);
        }
    } else {
        // ---------- qkv projection via MFMA (wave = 16 nodes x 192 cols) ----
        // A frag: lane holds x[row=l&15][k=(l>>4)*8+i]; B frag: Wbt[col][k].
        // D: col = l&15, row = (l>>4)*4 + reg  (m89-verified).
        // Epilogue: stage block's 128x192 f16 tile in LDS, bulk-write uint4.
        unsigned short* tile = (unsigned short*)smem;              // [128][TPAD]

        const int tid = threadIdx.x;
        const int lane = tid & 63;
        const int wid = tid >> 6;
        const int nb0 = (blockIdx.x - NBK) * 128;                  // block's first node
        const int n0 = nb0 + wid * 16;                             // wave's first node
        const bool active = n0 < N_NODES;                          // no early return: syncthreads below
        const int row = lane & 15;
        const int kg = lane >> 4;

        if (active) {
            const int nidx = min(n0 + row, N_NODES - 1);
            const float* xr = x + (size_t)nidx * DIM + kg * 8;
            short8 a0, a1;
            {
                const float4 u0 = *(const float4*)(xr);
                const float4 u1 = *(const float4*)(xr + 4);
                const float4 u2 = *(const float4*)(xr + 32);
                const float4 u3 = *(const float4*)(xr + 36);
                a0[0] = (short)f32_to_bf16_rne(u0.x); a0[1] = (short)f32_to_bf16_rne(u0.y);
                a0[2] = (short)f32_to_bf16_rne(u0.z); a0[3] = (short)f32_to_bf16_rne(u0.w);
                a0[4] = (short)f32_to_bf16_rne(u1.x); a0[5] = (short)f32_to_bf16_rne(u1.y);
                a0[6] = (short)f32_to_bf16_rne(u1.z); a0[7] = (short)f32_to_bf16_rne(u1.w);
                a1[0] = (short)f32_to_bf16_rne(u2.x); a1[1] = (short)f32_to_bf16_rne(u2.y);
                a1[2] = (short)f32_to_bf16_rne(u2.z); a1[3] = (short)f32_to_bf16_rne(u2.w);
                a1[4] = (short)f32_to_bf16_rne(u3.x); a1[5] = (short)f32_to_bf16_rne(u3.y);
                a1[6] = (short)f32_to_bf16_rne(u3.z); a1[7] = (short)f32_to_bf16_rne(u3.w);
            }

            #pragma unroll
            for (int ct = 0; ct < 12; ++ct) {
                const int c0 = ct * 16;
                const float bias = bb[c0 + row];
                f32x4 acc = {bias, bias, bias, bias};
                const short8 b0 = *(const short8*)(Wbt + (c0 + row) * DIM + kg * 8);
                const short8 b1 = *(const short8*)(Wbt + (c0 + row) * DIM + kg * 8 + 32);
                acc = __builtin_amdgcn_mfma_f32_16x16x32_bf16(a0, b0, acc, 0, 0, 0);
                acc = __builtin_amdgcn_mfma_f32_16x16x32_bf16(a1, b1, acc, 0, 0, 0);

                const int colg = c0 + row;
                #pragma unroll
                for (int r = 0; r < 4; ++r) {
                    const _Float16 hv = (_Float16)acc[r];          // RNE
                    tile[(wid * 16 + kg * 4 + r) * TPAD + colg] =
                        __builtin_bit_cast(unsigned short, hv);
                }
            }
        }
        __syncthreads();

        // bulk write: 128 rows x 192 shorts = 3072 uint4, 6 per thread, coalesced
        for (int i = tid; i < 128 * 24; i += 512) {
            const int r = i / 24, c = i % 24;
            if (nb0 + r < N_NODES) {
                const uint4 val = *(const uint4*)(tile + r * TPAD + c * 8);
                ((uint4*)(qkv_t + (size_t)(nb0 + r) * 192))[c] = val;
            }
        }
    }
}

// ---------------- Fused per-node attention (f16 dot2/fma_mix, clamped tails) --
// One wave per node; 16 edges per step; eg owns consecutive edges j+4eg..+3,
// targets loaded directly with CLAMPED index (re-hits hot line; no extra traffic).
// Per edge: 2x v_dot2_f32_f16 (QK) + 4x v_fma_mix_f32 (PV) — no unpack ops.
// Per-group online max, exact split-softmax merge. Finite sentinels.
__global__ __launch_bounds__(256) void node_pass(const unsigned short* __restrict__ qkv,
                                                 const int* __restrict__ off,
                                                 const int* __restrict__ deg,
                                                 const int* __restrict__ sorted_t,
                                                 float* __restrict__ out) {
    const int node = blockIdx.x * 4 + (threadIdx.x >> 6);
    const int lane = threadIdx.x & 63;
    if (node >= N_NODES) return;
    const int eg = lane >> 4;
    const int q16 = lane & 15;

    const int o = off[node];
    const int d = deg[node];

    // q (log2-domain, f16): lane's 4 dims = 2 packed pairs
    const uint2 qu = *(const uint2*)(qkv + (size_t)node * 192 + q16 * 4);
    const h2 q01 = as_h2(qu.x), q23 = as_h2(qu.y);

    const float M0 = -1e30f, MASKV = -2e30f;
    float m = M0;
    float l = 0.f;
    float4 acc = make_float4(0.f, 0.f, 0.f, 0.f);

    for (int j = 0; j < d; j += 16) {
        const int b0 = j + eg * 4;
        const int dm = d - 1;
        const int t0 = sorted_t[o + min(b0,     dm)];
        const int t1 = sorted_t[o + min(b0 + 1, dm)];
        const int t2 = sorted_t[o + min(b0 + 2, dm)];
        const int t3 = sorted_t[o + min(b0 + 3, dm)];
        const uint4 A0 = *(const uint4*)(qkv + (size_t)t0 * 192 + 64 + q16 * 8);
        const uint4 A1 = *(const uint4*)(qkv + (size_t)t1 * 192 + 64 + q16 * 8);
        const uint4 A2 = *(const uint4*)(qkv + (size_t)t2 * 192 + 64 + q16 * 8);
        const uint4 A3 = *(const uint4*)(qkv + (size_t)t3 * 192 + 64 + q16 * 8);
        // QK dots: packed f16 pairs straight from the loads
        float p0 = fdot2_acc(as_h2(A0.y), q23, fdot2_acc(as_h2(A0.x), q01, 0.f));
        float p1 = fdot2_acc(as_h2(A1.y), q23, fdot2_acc(as_h2(A1.x), q01, 0.f));
        float p2 = fdot2_acc(as_h2(A2.y), q23, fdot2_acc(as_h2(A2.x), q01, 0.f));
        float p3 = fdot2_acc(as_h2(A3.y), q23, fdot2_acc(as_h2(A3.x), q01, 0.f));
        p0 = qsum4(p0); p1 = qsum4(p1); p2 = qsum4(p2); p3 = qsum4(p3);
        p0 = (b0     < d) ? p0 : MASKV;
        p1 = (b0 + 1 < d) ? p1 : MASKV;
        p2 = (b0 + 2 < d) ? p2 : MASKV;
        p3 = (b0 + 3 < d) ? p3 : MASKV;
        const float pm = fmaxf(fmaxf(p0, p1), fmaxf(p2, p3));   // this group's max
        if (__any(pm > m)) {
            const float nm = fmaxf(m, pm);
            const float sc = exp2f(m - nm);    // finite-finite: no NaN
            l *= sc;
            acc.x *= sc; acc.y *= sc; acc.z *= sc; acc.w *= sc;
            m = nm;
        }
        const float e0 = exp2f(p0 - m);        // masked: exp2(~-1e30) = 0
        const float e1 = exp2f(p1 - m);
        const float e2 = exp2f(p2 - m);
        const float e3 = exp2f(p3 - m);
        l += (e0 + e1) + (e2 + e3);
        // PV: f16 halves consumed via v_fma_mix_f32 (fpext folds into the fma)
        const h2 va0 = as_h2(A0.z), vb0 = as_h2(A0.w);
        const h2 va1 = as_h2(A1.z), vb1 = as_h2(A1.w);
        const h2 va2 = as_h2(A2.z), vb2 = as_h2(A2.w);
        const h2 va3 = as_h2(A3.z), vb3 = as_h2(A3.w);
        acc.x = fmaf(e0, (float)va0.x, fmaf(e1, (float)va1.x,
                fmaf(e2, (float)va2.x, fmaf(e3, (float)va3.x, acc.x))));
        acc.y = fmaf(e0, (float)va0.y, fmaf(e1, (float)va1.y,
                fmaf(e2, (float)va2.y, fmaf(e3, (float)va3.y, acc.y))));
        acc.z = fmaf(e0, (float)vb0.x, fmaf(e1, (float)vb1.x,
                fmaf(e2, (float)vb2.x, fmaf(e3, (float)vb3.x, acc.z))));
        acc.w = fmaf(e0, (float)vb0.y, fmaf(e1, (float)vb1.y,
                fmaf(e2, (float)vb2.y, fmaf(e3, (float)vb3.y, acc.w))));
    }

    // exact split-softmax merge across the 4 edge-groups
    float M = fmaxf(m, __shfl_xor(m, 16));
    M = fmaxf(M, __shfl_xor(M, 32));
    const float s = exp2f(m - M);              // empty group: 0; d==0: 1, l=0
    l *= s;
    acc.x *= s; acc.y *= s; acc.z *= s; acc.w *= s;

    l += __shfl_xor(l, 16);  l += __shfl_xor(l, 32);
    acc.x += __shfl_xor(acc.x, 16);  acc.x += __shfl_xor(acc.x, 32);
    acc.y += __shfl_xor(acc.y, 16);  acc.y += __shfl_xor(acc.y, 32);
    acc.z += __shfl_xor(acc.z, 16);  acc.z += __shfl_xor(acc.z, 32);
    acc.w += __shfl_xor(acc.w, 16);  acc.w += __shfl_xor(acc.w, 32);

    if (eg == 0) {
        const float inv = 1.f / (l + EPS);
        float4 r = make_float4(acc.x * inv, acc.y * inv, acc.z * inv, acc.w * inv);
        *(float4*)(out + (size_t)node * DIM + q16 * 4) = r;
    }
}

extern "C" void kernel_launch(void* const* d_in, const int* in_sizes, int n_in,
                              void* d_out, int out_size, void* d_ws, size_t ws_size,
                              hipStream_t stream) {
    const float* x = (const float*)d_in[0];
    const float* W = (const float*)d_in[1];
    const float* b = (const float*)d_in[2];
    const int*   ei = (const int*)d_in[3];   // (2, E): [0:E]=src, [E:2E]=tgt
    float* out = (float*)d_out;

    // workspace: qkv_t 38.4MB | bbuf 12.8MB | sorted_t 6.4MB | deg | off | bcnt | Wbt | bb
    unsigned short* qkv_t = (unsigned short*)d_ws;
    unsigned int* bbuf = (unsigned int*)(qkv_t + (size_t)N_NODES * 192);
    int* sorted_t = (int*)(bbuf + (size_t)NBK * BCAP);
    int* deg      = sorted_t + N_EDGES;
    int* off      = deg + N_NODES;
    int* bcnt     = off + N_NODES;
    unsigned short* Wbt = (unsigned short*)(bcnt + NBK);   // 192*64 bf16
    float* bb     = (float*)(Wbt + 192 * DIM);             // 192 f32

    hipMemsetAsync(bcnt, 0, NBK * sizeof(int), stream);
    scatter_prep<<<SC_BLOCKS + 64, 512, 0, stream>>>(ei, bcnt, bbuf, W, b, Wbt, bb);
    csr_qkv<<<NBK + QK_BLOCKS, 512, 0, stream>>>(bcnt, bbuf, deg, off, sorted_t,
                                                 x, Wbt, bb, qkv_t);
    node_pass<<<(N_NODES + 3) / 4, 256, 0, stream>>>(qkv_t, off, deg, sorted_t, out);
}

// Round 18
// 114.009 us; speedup vs baseline: 1.1419x; 1.1419x over previous
//
#include <hip/hip_runtime.h>

// SelfAttentionBlock: graph transformer attention
// N=100000 nodes, E=1600000 edges, DIM=64, H=4 heads, d=16
constexpr int N_NODES = 100000;
constexpr int N_EDGES = 1600000;
constexpr int DIM = 64;
constexpr float QK_SCALE = 0.25f;   // 16^-0.5
constexpr float LOG2E = 1.4426950408889634f;
constexpr float EPS = 1e-16f;

// bucket sort: bucket = s>>8 (256 nodes each)
constexpr int NBK = (N_NODES + 255) / 256;    // 391
constexpr int BCAP = 8192;                    // u32/bucket
constexpr int SC_CHUNK = 8192;                // edges per scatter block (dense ~21-edge runs)
constexpr int SC_BLOCKS = (N_EDGES + SC_CHUNK - 1) / SC_CHUNK;  // 196
constexpr int QK_BLOCKS = (N_NODES + 127) / 128;                // 782 (128 nodes/block)
constexpr int TPAD = 200;                     // LDS tile row stride (shorts)

typedef __attribute__((ext_vector_type(8))) short short8;   // 8 bf16 (4 VGPR)
typedef __attribute__((ext_vector_type(4))) float f32x4;
typedef _Float16 h2 __attribute__((ext_vector_type(2)));

__device__ __forceinline__ unsigned short f32_to_bf16_rne(float f) {
    unsigned int u = __float_as_uint(f);
    u += 0x7fffu + ((u >> 16) & 1u);          // round-to-nearest-even
    return (unsigned short)(u >> 16);
}
__device__ __forceinline__ h2 as_h2(unsigned int u) { return __builtin_bit_cast(h2, u); }

#if defined(__has_builtin)
#if __has_builtin(__builtin_amdgcn_fdot2)
#define HAVE_FDOT2 1
#endif
#endif
__device__ __forceinline__ float fdot2_acc(h2 a, h2 b, float c) {
#ifdef HAVE_FDOT2
    return __builtin_amdgcn_fdot2(a, b, c, false);      // v_dot2_f32_f16
#else
    return fmaf((float)a.x, (float)b.x, fmaf((float)a.y, (float)b.y, c));
#endif
}

// sum over 4-lane quad via DPP (quad_perm xor1 = 0xB1, xor2 = 0x4E) - pure VALU
__device__ __forceinline__ float qsum4(float p) {
    int a = __builtin_amdgcn_update_dpp(0, __float_as_int(p), 0xB1, 0xF, 0xF, true);
    p += __int_as_float(a);
    int c = __builtin_amdgcn_update_dpp(0, __float_as_int(p), 0x4E, 0xF, 0xF, true);
    p += __int_as_float(c);
    return p;
}

// permuted output column jp -> original W column.
// jp 0..63: q cols. jp 64..191: interleaved kv layout [k0..3 v0..3 k4..7 ...]
__device__ __forceinline__ int orig_col(int jp) {
    if (jp < 64) return jp;
    const int p = jp - 64;
    const int chunk = p >> 3, w = p & 7;
    return (w < 4) ? (64 + chunk * 4 + w) : (128 + chunk * 4 + (w - 4));
}

// ---------------- prep: Wbt[jp][k] bf16 (permuted cols; q cols scaled by
// QK_SCALE*log2e for exp2-domain softmax), bias bb[jp] f32, bcnt zeroing.
__global__ __launch_bounds__(192) void prep_w(const float* __restrict__ W,
                                              const float* __restrict__ b,
                                              unsigned short* __restrict__ Wbt,
                                              float* __restrict__ bb,
                                              int* __restrict__ bcnt) {
    const int jp = threadIdx.x;
    const int k = blockIdx.x;
    const int oc = orig_col(jp);
    const float sc = (jp < 64) ? QK_SCALE * LOG2E : 1.f;
    Wbt[jp * DIM + k] = f32_to_bf16_rne(W[k * 192 + oc] * sc);
    if (k == 0) {
        bb[jp] = b[oc] * sc;
        for (int i = jp; i < NBK; i += 192) bcnt[i] = 0;
    }
}

// ---------------- Packed kernel: bucket_scatter (blocks 0..SC_BLOCKS-1)
//                  + qkv projection via MFMA (remaining blocks) -------------
// Branches are block-uniform; both alias one LDS buffer.
// qkv_t row (192 f16): [q(64, log2-domain) | kv(128 interleaved)]
__global__ __launch_bounds__(512) void proj_scatter(const float* __restrict__ x,
                                                    const unsigned short* __restrict__ Wbt,
                                                    const float* __restrict__ bb,
                                                    unsigned short* __restrict__ qkv_t,
                                                    const int* __restrict__ ei,
                                                    int* __restrict__ bcnt,
                                                    unsigned int* __restrict__ bbuf) {
    __shared__ __align__(16) char smem[128 * TPAD * 2];   // 51200 B, aliased by both branches

    if (blockIdx.x < SC_BLOCKS) {
        // ---------- bucket scatter with LDS dense staging ----------
        // Payload packed: bits 0..16 = t, bits 17..24 = s&255.
        unsigned int* stage = (unsigned int*)smem;                 // [SC_CHUNK] 32768 B
        int* h     = (int*)(smem + SC_CHUNK * 4);                  // [NBK]
        int* lofs  = h + NBK;
        int* gbase = lofs + NBK;
        int* wsum  = gbase + NBK;                                  // [8]

        const int tid = threadIdx.x;
        const int lane = tid & 63;
        const int wid = tid >> 6;
        const int e0 = blockIdx.x * SC_CHUNK;
        const int n = min(SC_CHUNK, N_EDGES - e0);                 // always %4 == 0
        const int n4 = n >> 2;

        for (int i = tid; i < NBK; i += 512) h[i] = 0;
        __syncthreads();

        // phase 1: histogram of s (int4 loads)
        const int4* s4p = (const int4*)(ei + e0);
        for (int i = tid; i < n4; i += 512) {
            const int4 s4 = s4p[i];
            atomicAdd(&h[s4.x >> 8], 1);
            atomicAdd(&h[s4.y >> 8], 1);
            atomicAdd(&h[s4.z >> 8], 1);
            atomicAdd(&h[s4.w >> 8], 1);
        }
        __syncthreads();

        const int v = (tid < NBK) ? h[tid] : 0;
        int inc = v;
        #pragma unroll
        for (int d = 1; d < 64; d <<= 1) {
            int u = __shfl_up(inc, d);
            if (lane >= d) inc += u;
        }
        if (lane == 63) wsum[wid] = inc;
        __syncthreads();
        int woff = 0;
        for (int w = 0; w < wid; ++w) woff += wsum[w];
        if (tid < NBK) lofs[tid] = woff + inc - v;
        if (tid < NBK) gbase[tid] = (v > 0) ? atomicAdd(&bcnt[tid], v) : 0;
        __syncthreads();

        for (int i = tid; i < NBK; i += 512) h[i] = 0;
        __syncthreads();

        // phase 3: dense placement (int4 loads of s and t)
        const int4* t4p = (const int4*)(ei + N_EDGES + e0);
        for (int i = tid; i < n4; i += 512) {
            const int4 s4 = s4p[i];
            const int4 t4 = t4p[i];
            #pragma unroll
            for (int k = 0; k < 4; ++k) {
                const int s = (k == 0) ? s4.x : (k == 1) ? s4.y : (k == 2) ? s4.z : s4.w;
                const int t = (k == 0) ? t4.x : (k == 1) ? t4.y : (k == 2) ? t4.z : t4.w;
                const int bk = s >> 8;
                const int c = atomicAdd(&h[bk], 1);
                stage[lofs[bk] + c] = (unsigned int)t | ((unsigned int)(s & 255) << 17);
            }
        }
        __syncthreads();

        // phase 4: flush contiguous runs; 16-LANE groups (runs avg ~21 edges,
        // so 16 lanes hit ~66% utilization vs 16% at 64 lanes)
        const int grp = tid >> 4;        // 0..31
        const int sub = tid & 15;
        for (int bk = grp; bk < NBK; bk += 32) {
            const int cnt = h[bk];
            const int lo = lofs[bk];
            unsigned int* dst = bbuf + (size_t)bk * BCAP + gbase[bk];
            for (int i = sub; i < cnt; i += 16) dst[i] = stage[lo + i];
        }
    } else {
        // ---------- qkv projection via MFMA (wave = 16 nodes x 192 cols) ----
        // A frag: lane holds x[row=l&15][k=(l>>4)*8+i]; B frag: Wbt[col][k].
        // D: col = l&15, row = (l>>4)*4 + reg  (m89-verified).
        // Epilogue: stage block's 128x192 f16 tile in LDS, bulk-write uint4.
        unsigned short* tile = (unsigned short*)smem;              // [128][TPAD]

        const int tid = threadIdx.x;
        const int lane = tid & 63;
        const int wid = tid >> 6;
        const int nb0 = (blockIdx.x - SC_BLOCKS) * 128;            // block's first node
        const int n0 = nb0 + wid * 16;                             // wave's first node
        const bool active = n0 < N_NODES;                          // no early return: syncthreads below
        const int row = lane & 15;
        const int kg = lane >> 4;

        if (active) {
            const int nidx = min(n0 + row, N_NODES - 1);
            const float* xr = x + (size_t)nidx * DIM + kg * 8;
            short8 a0, a1;
            {
                const float4 u0 = *(const float4*)(xr);
                const float4 u1 = *(const float4*)(xr + 4);
                const float4 u2 = *(const float4*)(xr + 32);
                const float4 u3 = *(const float4*)(xr + 36);
                a0[0] = (short)f32_to_bf16_rne(u0.x); a0[1] = (short)f32_to_bf16_rne(u0.y);
                a0[2] = (short)f32_to_bf16_rne(u0.z); a0[3] = (short)f32_to_bf16_rne(u0.w);
                a0[4] = (short)f32_to_bf16_rne(u1.x); a0[5] = (short)f32_to_bf16_rne(u1.y);
                a0[6] = (short)f32_to_bf16_rne(u1.z); a0[7] = (short)f32_to_bf16_rne(u1.w);
                a1[0] = (short)f32_to_bf16_rne(u2.x); a1[1] = (short)f32_to_bf16_rne(u2.y);
                a1[2] = (short)f32_to_bf16_rne(u2.z); a1[3] = (short)f32_to_bf16_rne(u2.w);
                a1[4] = (short)f32_to_bf16_rne(u3.x); a1[5] = (short)f32_to_bf16_rne(u3.y);
                a1[6] = (short)f32_to_bf16_rne(u3.z); a1[7] = (short)f32_to_bf16_rne(u3.w);
            }

            #pragma unroll
            for (int ct = 0; ct < 12; ++ct) {
                const int c0 = ct * 16;
                const float bias = bb[c0 + row];
                f32x4 acc = {bias, bias, bias, bias};
                const short8 b0 = *(const short8*)(Wbt + (c0 + row) * DIM + kg * 8);
                const short8 b1 = *(const short8*)(Wbt + (c0 + row) * DIM + kg * 8 + 32);
                acc = __builtin_amdgcn_mfma_f32_16x16x32_bf16(a0, b0, acc, 0, 0, 0);
                acc = __builtin_amdgcn_mfma_f32_16x16x32_bf16(a1, b1, acc, 0, 0, 0);

                const int colg = c0 + row;
                #pragma unroll
                for (int r = 0; r < 4; ++r) {
                    const _Float16 hv = (_Float16)acc[r];          // RNE
                    tile[(wid * 16 + kg * 4 + r) * TPAD + colg] =
                        __builtin_bit_cast(unsigned short, hv);
                }
            }
        }
        __syncthreads();

        // bulk write: 128 rows x 192 shorts = 3072 uint4, 6 per thread, coalesced
        for (int i = tid; i < 128 * 24; i += 512) {
            const int r = i / 24, c = i % 24;
            if (nb0 + r < N_NODES) {
                const uint4 val = *(const uint4*)(tile + r * TPAD + c * 8);
                ((uint4*)(qkv_t + (size_t)(nb0 + r) * 192))[c] = val;
            }
        }
    }
}

// ---------------- Fused CSR build: deg + off + sorted_t (1 block/bucket) ----
// 512 threads: halves per-thread serial work; 256-bin scan on first 256 threads.
__global__ __launch_bounds__(512) void csr_build(const int* __restrict__ bcnt,
                                                 const unsigned int* __restrict__ bbuf,
                                                 int* __restrict__ deg,
                                                 int* __restrict__ off,
                                                 int* __restrict__ sorted_t) {
    __shared__ int h[256];
    __shared__ int lofs[256];
    __shared__ int wsum[8];
    __shared__ int sBase;

    const int tid = threadIdx.x;
    const int lane = tid & 63;
    const int wid = tid >> 6;
    const int bk = blockIdx.x;
    const int n = bcnt[bk];

    // bucket edge base = sum of bcnt[0..bk)  (all 8 waves)
    int pre = 0;
    for (int i = tid; i < bk; i += 512) pre += bcnt[i];
    #pragma unroll
    for (int d = 1; d < 64; d <<= 1) pre += __shfl_xor(pre, d);
    if (lane == 0) wsum[wid] = pre;
    if (tid < 256) h[tid] = 0;
    __syncthreads();
    if (tid == 0) {
        int s = 0;
        #pragma unroll
        for (int w = 0; w < 8; ++w) s += wsum[w];
        sBase = s;
    }
    __syncthreads();

    // histogram of s&255 within bucket (all 8 waves)
    const unsigned int* p = bbuf + (size_t)bk * BCAP;
    for (int i = tid; i < n; i += 512)
        atomicAdd(&h[p[i] >> 17], 1);
    __syncthreads();

    // exclusive scan of h[256] on threads 0..255 (4 waves)
    int v = 0, inc = 0;
    if (tid < 256) {
        v = h[tid];
        inc = v;
        #pragma unroll
        for (int d = 1; d < 64; d <<= 1) {
            int u = __shfl_up(inc, d);
            if (lane >= d) inc += u;
        }
        if (lane == 63) wsum[wid] = inc;
    }
    __syncthreads();
    if (tid < 256) {
        int woff = 0;
        for (int w = 0; w < wid; ++w) woff += wsum[w];
        const int exc = woff + inc - v;
        lofs[tid] = exc;
        const int node = bk * 256 + tid;
        if (node < N_NODES) { deg[node] = v; off[node] = sBase + exc; }
    }
    __syncthreads();

    if (tid < 256) h[tid] = 0;
    __syncthreads();
    int* dstbase = sorted_t + sBase;
    for (int i = tid; i < n; i += 512) {
        const unsigned int e = p[i];
        const int s8 = e >> 17;
        const int c = atomicAdd(&h[s8], 1);
        dstbase[lofs[s8] + c] = (int)(e & 0x1FFFFu);
    }
}

// ---------------- Fused per-node attention (f16 dot2/fma_mix, clamped tails) --
// One wave per node; 16 edges per step; eg owns consecutive edges j+4eg..+3,
// targets loaded directly with CLAMPED index (re-hits hot line; no extra traffic).
// Per edge: 2x v_dot2_f32_f16 (QK) + 4x v_fma_mix_f32 (PV) — no unpack ops.
// Per-group online max, exact split-softmax merge. Finite sentinels.
__global__ __launch_bounds__(256) void node_pass(const unsigned short* __restrict__ qkv,
                                                 const int* __restrict__ off,
                                                 const int* __restrict__ deg,
                                                 const int* __restrict__ sorted_t,
                                                 float* __restrict__ out) {
    const int node = blockIdx.x * 4 + (threadIdx.x >> 6);
    const int lane = threadIdx.x & 63;
    if (node >= N_NODES) return;
    const int eg = lane >> 4;
    const int q16 = lane & 15;

    const int o = off[node];
    const int d = deg[node];

    // q (log2-domain, f16): lane's 4 dims = 2 packed pairs
    const uint2 qu = *(const uint2*)(qkv + (size_t)node * 192 + q16 * 4);
    const h2 q01 = as_h2(qu.x), q23 = as_h2(qu.y);

    const float M0 = -1e30f, MASKV = -2e30f;
    float m = M0;
    float l = 0.f;
    float4 acc = make_float4(0.f, 0.f, 0.f, 0.f);

    for (int j = 0; j < d; j += 16) {
        const int b0 = j + eg * 4;
        const int dm = d - 1;
        const int t0 = sorted_t[o + min(b0,     dm)];
        const int t1 = sorted_t[o + min(b0 + 1, dm)];
        const int t2 = sorted_t[o + min(b0 + 2, dm)];
        const int t3 = sorted_t[o + min(b0 + 3, dm)];
        const uint4 A0 = *(const uint4*)(qkv + (size_t)t0 * 192 + 64 + q16 * 8);
        const uint4 A1 = *(const uint4*)(qkv + (size_t)t1 * 192 + 64 + q16 * 8);
        const uint4 A2 = *(const uint4*)(qkv + (size_t)t2 * 192 + 64 + q16 * 8);
        const uint4 A3 = *(const uint4*)(qkv + (size_t)t3 * 192 + 64 + q16 * 8);
        // QK dots: packed f16 pairs straight from the loads
        float p0 = fdot2_acc(as_h2(A0.y), q23, fdot2_acc(as_h2(A0.x), q01, 0.f));
        float p1 = fdot2_acc(as_h2(A1.y), q23, fdot2_acc(as_h2(A1.x), q01, 0.f));
        float p2 = fdot2_acc(as_h2(A2.y), q23, fdot2_acc(as_h2(A2.x), q01, 0.f));
        float p3 = fdot2_acc(as_h2(A3.y), q23, fdot2_acc(as_h2(A3.x), q01, 0.f));
        p0 = qsum4(p0); p1 = qsum4(p1); p2 = qsum4(p2); p3 = qsum4(p3);
        p0 = (b0     < d) ? p0 : MASKV;
        p1 = (b0 + 1 < d) ? p1 : MASKV;
        p2 = (b0 + 2 < d) ? p2 : MASKV;
        p3 = (b0 + 3 < d) ? p3 : MASKV;
        const float pm = fmaxf(fmaxf(p0, p1), fmaxf(p2, p3));   // this group's max
        if (__any(pm > m)) {
            const float nm = fmaxf(m, pm);
            const float sc = exp2f(m - nm);    // finite-finite: no NaN
            l *= sc;
            acc.x *= sc; acc.y *= sc; acc.z *= sc; acc.w *= sc;
            m = nm;
        }
        const float e0 = exp2f(p0 - m);        // masked: exp2(~-1e30) = 0
        const float e1 = exp2f(p1 - m);
        const float e2 = exp2f(p2 - m);
        const float e3 = exp2f(p3 - m);
        l += (e0 + e1) + (e2 + e3);
        // PV: f16 halves consumed via v_fma_mix_f32 (fpext folds into the fma)
        const h2 va0 = as_h2(A0.z), vb0 = as_h2(A0.w);
        const h2 va1 = as_h2(A1.z), vb1 = as_h2(A1.w);
        const h2 va2 = as_h2(A2.z), vb2 = as_h2(A2.w);
        const h2 va3 = as_h2(A3.z), vb3 = as_h2(A3.w);
        acc.x = fmaf(e0, (float)va0.x, fmaf(e1, (float)va1.x,
                fmaf(e2, (float)va2.x, fmaf(e3, (float)va3.x, acc.x))));
        acc.y = fmaf(e0, (float)va0.y, fmaf(e1, (float)va1.y,
                fmaf(e2, (float)va2.y, fmaf(e3, (float)va3.y, acc.y))));
        acc.z = fmaf(e0, (float)vb0.x, fmaf(e1, (float)vb1.x,
                fmaf(e2, (float)vb2.x, fmaf(e3, (float)vb3.x, acc.z))));
        acc.w = fmaf(e0, (float)vb0.y, fmaf(e1, (float)vb1.y,
                fmaf(e2, (float)vb2.y, fmaf(e3, (float)vb3.y, acc.w))));
    }

    // exact split-softmax merge across the 4 edge-groups
    float M = fmaxf(m, __shfl_xor(m, 16));
    M = fmaxf(M, __shfl_xor(M, 32));
    const float s = exp2f(m - M);              // empty group: 0; d==0: 1, l=0
    l *= s;
    acc.x *= s; acc.y *= s; acc.z *= s; acc.w *= s;

    l += __shfl_xor(l, 16);  l += __shfl_xor(l, 32);
    acc.x += __shfl_xor(acc.x, 16);  acc.x += __shfl_xor(acc.x, 32);
    acc.y += __shfl_xor(acc.y, 16);  acc.y += __shfl_xor(acc.y, 32);
    acc.z += __shfl_xor(acc.z, 16);  acc.z += __shfl_xor(acc.z, 32);
    acc.w += __shfl_xor(acc.w, 16);  acc.w += __shfl_xor(acc.w, 32);

    if (eg == 0) {
        const float inv = 1.f / (l + EPS);
        float4 r = make_float4(acc.x * inv, acc.y * inv, acc.z * inv, acc.w * inv);
        *(float4*)(out + (size_t)node * DIM + q16 * 4) = r;
    }
}

extern "C" void kernel_launch(void* const* d_in, const int* in_sizes, int n_in,
                              void* d_out, int out_size, void* d_ws, size_t ws_size,
                              hipStream_t stream) {
    const float* x = (const float*)d_in[0];
    const float* W = (const float*)d_in[1];
    const float* b = (const float*)d_in[2];
    const int*   ei = (const int*)d_in[3];   // (2, E): [0:E]=src, [E:2E]=tgt
    float* out = (float*)d_out;

    // workspace: qkv_t 38.4MB | bbuf 12.8MB | sorted_t 6.4MB | deg | off | bcnt | Wbt | bb
    unsigned short* qkv_t = (unsigned short*)d_ws;
    unsigned int* bbuf = (unsigned int*)(qkv_t + (size_t)N_NODES * 192);
    int* sorted_t = (int*)(bbuf + (size_t)NBK * BCAP);
    int* deg      = sorted_t + N_EDGES;
    int* off      = deg + N_NODES;
    int* bcnt     = off + N_NODES;
    unsigned short* Wbt = (unsigned short*)(bcnt + NBK);   // 192*64 bf16
    float* bb     = (float*)(Wbt + 192 * DIM);             // 192 f32

    prep_w<<<64, 192, 0, stream>>>(W, b, Wbt, bb, bcnt);
    proj_scatter<<<SC_BLOCKS + QK_BLOCKS, 512, 0, stream>>>(x, Wbt, bb, qkv_t, ei, bcnt, bbuf);
    csr_build<<<NBK, 512, 0, stream>>>(bcnt, bbuf, deg, off, sorted_t);
    node_pass<<<(N_NODES + 3) / 4, 256, 0, stream>>>(qkv_t, off, deg, sorted_t, out);
}